// Round 3
// baseline (532.519 us; speedup 1.0000x reference)
//
#include <hip/hip_runtime.h>

// Problem geometry (fixed by setup_inputs)
#define BB 32
#define DD 64
#define HWSZ 4096                  // H*W
#define KK 1024
#define NPIX (BB*HWSZ)             // 131072
#define NELEM (NPIX*DD)            // 8388608

// Output layout (concatenated float32)
#define IDX_OUT_OFF NELEM
#define LOSS_OFF (IDX_OUT_OFF + NPIX)

// Workspace layout (bytes)
#define WS_E2   0
#define WS_IDX  (WS_E2 + KK*4)
#define WS_PART (WS_IDX + NPIX*4)

#define NBLK_MAIN (NPIX/256)       // 512

// ---------------------------------------------------------------------------
// numpy-style fp32 sum of 64 squares: each square rounded separately (numpy
// materializes x*x then pairwise-sums), 8-accumulator pairwise pattern.
// contract(off) so hipcc cannot fuse mul+add (default -ffp-contract=fast).
__device__ __forceinline__ float np_sumsq64(const float* a) {
#pragma clang fp contract(off)
    float r0=0.f,r1=0.f,r2=0.f,r3=0.f,r4=0.f,r5=0.f,r6=0.f,r7=0.f;
#pragma unroll
    for (int i = 0; i < 64; i += 8) {
        r0 += a[i+0]*a[i+0];
        r1 += a[i+1]*a[i+1];
        r2 += a[i+2]*a[i+2];
        r3 += a[i+3]*a[i+3];
        r4 += a[i+4]*a[i+4];
        r5 += a[i+5]*a[i+5];
        r6 += a[i+6]*a[i+6];
        r7 += a[i+7]*a[i+7];
    }
    return ((r0+r1)+(r2+r3))+((r4+r5)+(r6+r7));
}

// ---------------------------------------------------------------------------
// Kernel 0: e2[k] = fp32 sum of squares of codebook row k (numpy semantics).
__global__ __launch_bounds__(256) void vq_e2(const float* __restrict__ emb,
                                             float* __restrict__ e2) {
    int k = blockIdx.x * blockDim.x + threadIdx.x;
    float ek[DD];
    const float4* p = reinterpret_cast<const float4*>(emb + (size_t)k * DD);
#pragma unroll
    for (int q = 0; q < 16; ++q) {
        float4 v = p[q];
        ek[4*q+0]=v.x; ek[4*q+1]=v.y; ek[4*q+2]=v.z; ek[4*q+3]=v.w;
    }
    e2[k] = np_sumsq64(ek);
}

// ---------------------------------------------------------------------------
// Kernel 1: bit-faithful fp32 emulation of
//   dists[n,k] = fl32( fl32(z2[n] + e2[k]) - 2*dot_f32[n,k] )
// with dot_f32 = sequential fp32 FMA chain over d=0..63 (sgemm semantics),
// argmin with first-min tie-break (numpy argmin).
__global__ __launch_bounds__(256) void vq_argmin_emul(
        const float* __restrict__ z, const float* __restrict__ emb,
        const float* __restrict__ e2, int* __restrict__ idx_out) {
    int n  = blockIdx.x * blockDim.x + threadIdx.x;   // pixel id
    int b  = n >> 12;
    int hw = n & 4095;
    const float* zp = z + (size_t)b * DD * HWSZ + hw;

    float zr[DD];
#pragma unroll
    for (int d = 0; d < DD; ++d) zr[d] = zp[(size_t)d * HWSZ];  // coalesced

    float z2 = np_sumsq64(zr);

    float best = 3.4e38f;
    int   bi   = 0;
    for (int k0 = 0; k0 < KK; k0 += 4) {              // 4 chains for ILP
        const float4* eA = reinterpret_cast<const float4*>(emb + (size_t)(k0+0) * DD);
        const float4* eB = reinterpret_cast<const float4*>(emb + (size_t)(k0+1) * DD);
        const float4* eC = reinterpret_cast<const float4*>(emb + (size_t)(k0+2) * DD);
        const float4* eD = reinterpret_cast<const float4*>(emb + (size_t)(k0+3) * DD);
        float s0 = 0.f, s1 = 0.f, s2 = 0.f, s3 = 0.f;
#pragma unroll
        for (int q = 0; q < 16; ++q) {
            float4 v0 = eA[q], v1 = eB[q], v2 = eC[q], v3 = eD[q];
            float za = zr[4*q+0], zb = zr[4*q+1], zc = zr[4*q+2], zd = zr[4*q+3];
            // sequential FMA chain per k (ascending d) == BLAS sgemm k-loop
            s0 = __builtin_fmaf(za, v0.x, s0);
            s1 = __builtin_fmaf(za, v1.x, s1);
            s2 = __builtin_fmaf(za, v2.x, s2);
            s3 = __builtin_fmaf(za, v3.x, s3);
            s0 = __builtin_fmaf(zb, v0.y, s0);
            s1 = __builtin_fmaf(zb, v1.y, s1);
            s2 = __builtin_fmaf(zb, v2.y, s2);
            s3 = __builtin_fmaf(zb, v3.y, s3);
            s0 = __builtin_fmaf(zc, v0.z, s0);
            s1 = __builtin_fmaf(zc, v1.z, s1);
            s2 = __builtin_fmaf(zc, v2.z, s2);
            s3 = __builtin_fmaf(zc, v3.z, s3);
            s0 = __builtin_fmaf(zd, v0.w, s0);
            s1 = __builtin_fmaf(zd, v1.w, s1);
            s2 = __builtin_fmaf(zd, v2.w, s2);
            s3 = __builtin_fmaf(zd, v3.w, s3);
        }
        {
#pragma clang fp contract(off)
            // A = fl(z2+e2k); B = fl(A - 2*dot)   (2*dot exact: power of 2)
            float A0 = z2 + e2[k0+0];  float B0 = A0 - 2.0f*s0;
            float A1 = z2 + e2[k0+1];  float B1 = A1 - 2.0f*s1;
            float A2 = z2 + e2[k0+2];  float B2 = A2 - 2.0f*s2;
            float A3 = z2 + e2[k0+3];  float B3 = A3 - 2.0f*s3;
            // ordered first-min updates (numpy argmin tie-break)
            if (B0 < best) { best = B0; bi = k0+0; }
            if (B1 < best) { best = B1; bi = k0+1; }
            if (B2 < best) { best = B2; bi = k0+2; }
            if (B3 < best) { best = B3; bi = k0+3; }
        }
    }
    idx_out[n] = bi;
}

// ---------------------------------------------------------------------------
// Kernel 2: gather z_q, write z_q_st (+indices as float), partial loss sums.
__global__ __launch_bounds__(256) void vq_epilogue(
        const float* __restrict__ z, const float* __restrict__ emb,
        const int* __restrict__ idx, float* __restrict__ out,
        double* __restrict__ partial) {
    int n  = blockIdx.x * blockDim.x + threadIdx.x;
    int b  = n >> 12;
    int hw = n & 4095;
    const float* zp = z   + (size_t)b * DD * HWSZ + hw;
    float*       op = out + (size_t)b * DD * HWSZ + hw;
    int ki = idx[n];
    const float* ek = emb + (size_t)ki * DD;

    float lsum = 0.f;
#pragma unroll
    for (int d = 0; d < DD; ++d) {
        float e  = ek[d];
        float zv = zp[(size_t)d * HWSZ];
        op[(size_t)d * HWSZ] = e;            // z_q_st == z_q (ref: z_e+(z_q-z_e))
        float df = e - zv;
        lsum = __builtin_fmaf(df, df, lsum);
    }
    out[IDX_OUT_OFF + n] = (float)ki;

    __shared__ double sred[256];
    sred[threadIdx.x] = (double)lsum;
    __syncthreads();
#pragma unroll
    for (int s = 128; s > 0; s >>= 1) {
        if (threadIdx.x < s) sred[threadIdx.x] += sred[threadIdx.x + s];
        __syncthreads();
    }
    if (threadIdx.x == 0) partial[blockIdx.x] = sred[0];
}

// ---------------------------------------------------------------------------
// Kernel 3: deterministic final reduction -> losses.
__global__ __launch_bounds__(256) void vq_finalize(
        const double* __restrict__ part, float* __restrict__ out) {
    __shared__ double sred[256];
    int t = threadIdx.x;
    sred[t] = part[t] + part[t + 256];       // 512 partials
    __syncthreads();
#pragma unroll
    for (int s = 128; s > 0; s >>= 1) {
        if (t < s) sred[t] += sred[t + s];
        __syncthreads();
    }
    if (t == 0) {
        double m = sred[0] / (double)NELEM;
        out[LOSS_OFF]     = (float)m;          // vq_loss
        out[LOSS_OFF + 1] = (float)(0.25 * m); // commitment_loss
    }
}

// ---------------------------------------------------------------------------
extern "C" void kernel_launch(void* const* d_in, const int* in_sizes, int n_in,
                              void* d_out, int out_size, void* d_ws, size_t ws_size,
                              hipStream_t stream) {
    const float* z   = (const float*)d_in[0];
    const float* emb = (const float*)d_in[1];
    float* out = (float*)d_out;
    char*  ws  = (char*)d_ws;

    float*  e2   = (float*)(ws + WS_E2);
    int*    idx  = (int*)(ws + WS_IDX);
    double* part = (double*)(ws + WS_PART);

    vq_e2          <<<KK/256,    256, 0, stream>>>(emb, e2);
    vq_argmin_emul <<<NBLK_MAIN, 256, 0, stream>>>(z, emb, e2, idx);
    vq_epilogue    <<<NBLK_MAIN, 256, 0, stream>>>(z, emb, idx, out, part);
    vq_finalize    <<<1,         256, 0, stream>>>(part, out);
}

// Round 4
// 391.524 us; speedup vs baseline: 1.3601x; 1.3601x over previous
//
#include <hip/hip_runtime.h>

// Problem geometry (fixed by setup_inputs)
#define BB 32
#define DD 64
#define HWSZ 4096                  // H*W
#define KK 1024
#define NPIX (BB*HWSZ)             // 131072
#define NELEM (NPIX*DD)            // 8388608

// Output layout (concatenated float32)
#define IDX_OUT_OFF NELEM
#define LOSS_OFF (IDX_OUT_OFF + NPIX)

// Workspace layout (bytes)
#define WS_E2   0
#define WS_ET   (WS_E2 + KK*4)           // e_T[64][1024] = 256 KB
#define WS_IDX  (WS_ET + DD*KK*4)
#define WS_PART (WS_IDX + NPIX*4)

#define KPT 16                     // codes per thread per k-group

// ---------------------------------------------------------------------------
// numpy-style fp32 sum of 64 squares: squares rounded separately, pairwise-ish
// 8-accumulator sum. (Argmin is invariant to whole-ulp shifts of z2, so the
// exact summation order doesn't matter; separate rounding of squares does.)
__device__ __forceinline__ float np_sumsq64(const float* a) {
#pragma clang fp contract(off)
    float r0=0.f,r1=0.f,r2=0.f,r3=0.f,r4=0.f,r5=0.f,r6=0.f,r7=0.f;
#pragma unroll
    for (int i = 0; i < 64; i += 8) {
        r0 += a[i+0]*a[i+0];
        r1 += a[i+1]*a[i+1];
        r2 += a[i+2]*a[i+2];
        r3 += a[i+3]*a[i+3];
        r4 += a[i+4]*a[i+4];
        r5 += a[i+5]*a[i+5];
        r6 += a[i+6]*a[i+6];
        r7 += a[i+7]*a[i+7];
    }
    return ((r0+r1)+(r2+r3))+((r4+r5)+(r6+r7));
}

// ---------------------------------------------------------------------------
// Kernel 0: e2[k] = fp32 sum of squares of codebook row k.
__global__ __launch_bounds__(256) void vq_e2(const float* __restrict__ emb,
                                             float* __restrict__ e2) {
    int k = blockIdx.x * blockDim.x + threadIdx.x;
    float ek[DD];
    const float4* p = reinterpret_cast<const float4*>(emb + (size_t)k * DD);
#pragma unroll
    for (int q = 0; q < 16; ++q) {
        float4 v = p[q];
        ek[4*q+0]=v.x; ek[4*q+1]=v.y; ek[4*q+2]=v.z; ek[4*q+3]=v.w;
    }
    e2[k] = np_sumsq64(ek);
}

// ---------------------------------------------------------------------------
// Kernel 1: codebook transpose e_T[d][k] = emb[k][d] (256 KB, one-time).
__global__ __launch_bounds__(256) void vq_transpose(const float* __restrict__ emb,
                                                    float* __restrict__ eT) {
    int i = blockIdx.x * blockDim.x + threadIdx.x;   // over 64*1024
    int d = i >> 10;
    int k = i & 1023;
    eT[i] = emb[(size_t)k * DD + d];
}

// ---------------------------------------------------------------------------
// Kernel 2: register-tiled fp32-exact argmin.
//   dists[n,k] = fl32( fl32(z2[n] + e2[k]) - 2*dot[n,k] ),
//   dot = sequential fp32 FMA chain over d=0..63 (sgemm k-loop semantics),
//   first-min tie-break (numpy argmin).
// z row (64 floats) register-resident; KPT=16 accumulators; codebook slice
// e_T[d][k0:k0+16] is wave-uniform -> scalar loads on the SMEM pipe.
__global__ __launch_bounds__(128, 2) void vq_argmin2(
        const float* __restrict__ z, const float* __restrict__ eT,
        const float* __restrict__ e2, int* __restrict__ idx_out) {
    int n  = blockIdx.x * 128 + threadIdx.x;          // pixel id
    int b  = n >> 12;
    int hw = n & 4095;
    const float* zp = z + (size_t)b * (DD*HWSZ) + hw;

    float zr[DD];
#pragma unroll
    for (int d = 0; d < DD; ++d) zr[d] = zp[(size_t)d * HWSZ];  // coalesced

    float z2 = np_sumsq64(zr);

    float best = 3.4e38f;
    int   bi   = 0;
    for (int k0 = 0; k0 < KK; k0 += KPT) {
        float acc[KPT];
#pragma unroll
        for (int j = 0; j < KPT; ++j) acc[j] = 0.f;
#pragma unroll
        for (int d = 0; d < DD; ++d) {
            const float* ed = eT + d * KK + k0;       // uniform across lanes
            float zd = zr[d];
#pragma unroll
            for (int j = 0; j < KPT; ++j)
                acc[j] = __builtin_fmaf(zd, ed[j], acc[j]);  // d-ascending chain
        }
        {
#pragma clang fp contract(off)
#pragma unroll
            for (int j = 0; j < KPT; ++j) {
                float A = z2 + e2[k0 + j];            // fl(z2+e2k), one rounding
                float B = __builtin_fmaf(-2.0f, acc[j], A);  // fl(A-2*dot)
                if (B < best) { best = B; bi = k0 + j; }     // first-min order
            }
        }
    }
    idx_out[n] = bi;
}

// ---------------------------------------------------------------------------
// Kernel 3: gather z_q, write z_q_st (+indices as float), partial loss sums.
__global__ __launch_bounds__(256) void vq_epilogue(
        const float* __restrict__ z, const float* __restrict__ emb,
        const int* __restrict__ idx, float* __restrict__ out,
        double* __restrict__ partial) {
    int n  = blockIdx.x * blockDim.x + threadIdx.x;
    int b  = n >> 12;
    int hw = n & 4095;
    const float* zp = z   + (size_t)b * (DD*HWSZ) + hw;
    float*       op = out + (size_t)b * (DD*HWSZ) + hw;
    int ki = idx[n];
    const float* ek = emb + (size_t)ki * DD;

    float lsum = 0.f;
#pragma unroll
    for (int d = 0; d < DD; ++d) {
        float e  = ek[d];
        float zv = zp[(size_t)d * HWSZ];
        op[(size_t)d * HWSZ] = e;            // z_q_st == z_q (ref: z_e+(z_q-z_e))
        float df = e - zv;
        lsum = __builtin_fmaf(df, df, lsum);
    }
    out[IDX_OUT_OFF + n] = (float)ki;

    __shared__ double sred[256];
    sred[threadIdx.x] = (double)lsum;
    __syncthreads();
#pragma unroll
    for (int s = 128; s > 0; s >>= 1) {
        if (threadIdx.x < s) sred[threadIdx.x] += sred[threadIdx.x + s];
        __syncthreads();
    }
    if (threadIdx.x == 0) partial[blockIdx.x] = sred[0];
}

// ---------------------------------------------------------------------------
// Kernel 4: deterministic final reduction -> losses.
__global__ __launch_bounds__(256) void vq_finalize(
        const double* __restrict__ part, float* __restrict__ out) {
    __shared__ double sred[256];
    int t = threadIdx.x;
    sred[t] = part[t] + part[t + 256];       // 512 partials
    __syncthreads();
#pragma unroll
    for (int s = 128; s > 0; s >>= 1) {
        if (t < s) sred[t] += sred[t + s];
        __syncthreads();
    }
    if (t == 0) {
        double m = sred[0] / (double)NELEM;
        out[LOSS_OFF]     = (float)m;          // vq_loss
        out[LOSS_OFF + 1] = (float)(0.25 * m); // commitment_loss
    }
}

// ---------------------------------------------------------------------------
extern "C" void kernel_launch(void* const* d_in, const int* in_sizes, int n_in,
                              void* d_out, int out_size, void* d_ws, size_t ws_size,
                              hipStream_t stream) {
    const float* z   = (const float*)d_in[0];
    const float* emb = (const float*)d_in[1];
    float* out = (float*)d_out;
    char*  ws  = (char*)d_ws;

    float*  e2   = (float*)(ws + WS_E2);
    float*  eT   = (float*)(ws + WS_ET);
    int*    idx  = (int*)(ws + WS_IDX);
    double* part = (double*)(ws + WS_PART);

    vq_e2        <<<KK/256,          256, 0, stream>>>(emb, e2);
    vq_transpose <<<(DD*KK)/256,     256, 0, stream>>>(emb, eT);
    vq_argmin2   <<<NPIX/128,        128, 0, stream>>>(z, eT, e2, idx);
    vq_epilogue  <<<NPIX/256,        256, 0, stream>>>(z, emb, idx, out, part);
    vq_finalize  <<<1,               256, 0, stream>>>(part, out);
}

// Round 5
// 382.976 us; speedup vs baseline: 1.3905x; 1.0223x over previous
//
#include <hip/hip_runtime.h>

// Problem geometry (fixed by setup_inputs)
#define BB 32
#define DD 64
#define HWSZ 4096                  // H*W
#define KK 1024
#define NPIX (BB*HWSZ)             // 131072
#define NELEM (NPIX*DD)            // 8388608

// Output layout (concatenated float32)
#define IDX_OUT_OFF NELEM
#define LOSS_OFF (IDX_OUT_OFF + NPIX)

// Workspace layout (bytes)
#define WS_E2   0
#define WS_ET   (WS_E2 + KK*4)           // e_T[64][1024] = 256 KB
#define WS_PART (WS_ET + DD*KK*4)

#define BLK 256                    // pixels per block
#define NBLK (NPIX/BLK)            // 512
#define KPT 16                     // codes per k-group (accumulators/thread)

// ---------------------------------------------------------------------------
// numpy-style fp32 sum of 64 squares: squares rounded separately (no FMA
// fusion), 8-accumulator pairwise pattern. Matches the passing round-4 bits.
__device__ __forceinline__ float np_sumsq64(const float* a) {
#pragma clang fp contract(off)
    float r0=0.f,r1=0.f,r2=0.f,r3=0.f,r4=0.f,r5=0.f,r6=0.f,r7=0.f;
#pragma unroll
    for (int i = 0; i < 64; i += 8) {
        r0 += a[i+0]*a[i+0];
        r1 += a[i+1]*a[i+1];
        r2 += a[i+2]*a[i+2];
        r3 += a[i+3]*a[i+3];
        r4 += a[i+4]*a[i+4];
        r5 += a[i+5]*a[i+5];
        r6 += a[i+6]*a[i+6];
        r7 += a[i+7]*a[i+7];
    }
    return ((r0+r1)+(r2+r3))+((r4+r5)+(r6+r7));
}

// ---------------------------------------------------------------------------
// Kernel 0: e2[k] = fp32 sum of squares of codebook row k.
__global__ __launch_bounds__(256) void vq_e2(const float* __restrict__ emb,
                                             float* __restrict__ e2) {
    int k = blockIdx.x * blockDim.x + threadIdx.x;
    float ek[DD];
    const float4* p = reinterpret_cast<const float4*>(emb + (size_t)k * DD);
#pragma unroll
    for (int q = 0; q < 16; ++q) {
        float4 v = p[q];
        ek[4*q+0]=v.x; ek[4*q+1]=v.y; ek[4*q+2]=v.z; ek[4*q+3]=v.w;
    }
    e2[k] = np_sumsq64(ek);
}

// ---------------------------------------------------------------------------
// Kernel 1: codebook transpose e_T[d][k] = emb[k][d] (256 KB, one-time).
__global__ __launch_bounds__(256) void vq_transpose(const float* __restrict__ emb,
                                                    float* __restrict__ eT) {
    int i = blockIdx.x * blockDim.x + threadIdx.x;   // over 64*1024
    int d = i >> 10;
    int k = i & 1023;
    eT[i] = emb[(size_t)k * DD + d];
}

// ---------------------------------------------------------------------------
// Kernel 2 (fused): LDS-tiled fp32-exact argmin + z_q/index/loss outputs.
//   dists[n,k] = fl32( fl32(z2[n] + e2[k]) - 2*dot[n,k] ),
//   dot = sequential fp32 FMA chain over d=0..63 (same bits as round 4 PASS),
//   first-min tie-break.
// z tile [64 d][256 px] lives in LDS: ds_read_b32 with constant offsets,
// conflict-free (lane-consecutive). Codebook slice eT[d][k0..k0+15] is
// wave-uniform -> s_load_dwordx16 on the scalar pipe. VALU stream ~pure FMA.
__global__ __launch_bounds__(256, 2) void vq_argmin_fused(
        const float* __restrict__ z, const float* __restrict__ emb,
        const float* __restrict__ eT, const float* __restrict__ e2,
        float* __restrict__ out, double* __restrict__ partial) {
    __shared__ float zsh[DD * BLK];      // 64 KB
    __shared__ double sred[BLK];

    const int tid = threadIdx.x;
    const int b   = blockIdx.x >> 4;          // 16 blocks per batch image
    const int hw0 = (blockIdx.x & 15) * BLK;
    const float* zp = z + (size_t)b * (DD * HWSZ) + hw0;

    // ---- stage z tile: coalesced global -> LDS, layout [d][px] ----
#pragma unroll 8
    for (int d = 0; d < DD; ++d)
        zsh[d * BLK + tid] = zp[(size_t)d * HWSZ + tid];
    __syncthreads();

    // ---- z2 with numpy separate-square-rounding semantics ----
    float a[DD];
#pragma unroll
    for (int d = 0; d < DD; ++d) a[d] = zsh[d * BLK + tid];
    const float z2 = np_sumsq64(a);

    // ---- K loop: 64 groups of 16 codes ----
    float best = 3.4e38f;
    int   bi   = 0;
#pragma unroll 1
    for (int k0 = 0; k0 < KK; k0 += KPT) {
        float acc[KPT];
#pragma unroll
        for (int j = 0; j < KPT; ++j) acc[j] = 0.f;
#pragma unroll
        for (int d = 0; d < DD; ++d) {
            const float zd = zsh[d * BLK + tid];       // ds_read, const offset
            const float* ed = eT + d * KK + k0;        // wave-uniform
#pragma unroll
            for (int j = 0; j < KPT; ++j)
                acc[j] = __builtin_fmaf(zd, ed[j], acc[j]);  // d-ascending chain
        }
        {
#pragma clang fp contract(off)
#pragma unroll
            for (int j = 0; j < KPT; ++j) {
                float A = z2 + e2[k0 + j];                    // fl(z2+e2k)
                float B = __builtin_fmaf(-2.0f, acc[j], A);   // fl(A-2*dot)
                if (B < best) { best = B; bi = k0 + j; }      // first-min
            }
        }
    }

    // ---- fused epilogue: gather code row, write z_q_st + index, loss ----
    float* op = out + (size_t)b * (DD * HWSZ) + hw0 + tid;
    const float4* ek = reinterpret_cast<const float4*>(emb + (size_t)bi * DD);
    float lsum = 0.f;
#pragma unroll
    for (int q = 0; q < 16; ++q) {
        float4 v = ek[q];
        float e0 = v.x, e1 = v.y, e2v = v.z, e3 = v.w;
        int d = 4 * q;
        float zv0 = zsh[(d+0) * BLK + tid];
        float zv1 = zsh[(d+1) * BLK + tid];
        float zv2 = zsh[(d+2) * BLK + tid];
        float zv3 = zsh[(d+3) * BLK + tid];
        op[(size_t)(d+0) * HWSZ] = e0;
        op[(size_t)(d+1) * HWSZ] = e1;
        op[(size_t)(d+2) * HWSZ] = e2v;
        op[(size_t)(d+3) * HWSZ] = e3;
        float f0 = e0 - zv0, f1 = e1 - zv1, f2 = e2v - zv2, f3 = e3 - zv3;
        lsum = __builtin_fmaf(f0, f0, lsum);
        lsum = __builtin_fmaf(f1, f1, lsum);
        lsum = __builtin_fmaf(f2, f2, lsum);
        lsum = __builtin_fmaf(f3, f3, lsum);
    }
    out[IDX_OUT_OFF + blockIdx.x * BLK + tid] = (float)bi;

    // ---- deterministic per-block loss partial ----
    sred[tid] = (double)lsum;
    __syncthreads();
#pragma unroll
    for (int s = 128; s > 0; s >>= 1) {
        if (tid < s) sred[tid] += sred[tid + s];
        __syncthreads();
    }
    if (tid == 0) partial[blockIdx.x] = sred[0];
}

// ---------------------------------------------------------------------------
// Kernel 3: deterministic final reduction -> losses.
__global__ __launch_bounds__(256) void vq_finalize(
        const double* __restrict__ part, float* __restrict__ out) {
    __shared__ double sred[256];
    int t = threadIdx.x;
    sred[t] = part[t] + part[t + 256];       // 512 partials
    __syncthreads();
#pragma unroll
    for (int s = 128; s > 0; s >>= 1) {
        if (t < s) sred[t] += sred[t + s];
        __syncthreads();
    }
    if (t == 0) {
        double m = sred[0] / (double)NELEM;
        out[LOSS_OFF]     = (float)m;          // vq_loss
        out[LOSS_OFF + 1] = (float)(0.25 * m); // commitment_loss
    }
}

// ---------------------------------------------------------------------------
extern "C" void kernel_launch(void* const* d_in, const int* in_sizes, int n_in,
                              void* d_out, int out_size, void* d_ws, size_t ws_size,
                              hipStream_t stream) {
    const float* z   = (const float*)d_in[0];
    const float* emb = (const float*)d_in[1];
    float* out = (float*)d_out;
    char*  ws  = (char*)d_ws;

    float*  e2   = (float*)(ws + WS_E2);
    float*  eT   = (float*)(ws + WS_ET);
    double* part = (double*)(ws + WS_PART);

    vq_e2           <<<KK/256,      256, 0, stream>>>(emb, e2);
    vq_transpose    <<<(DD*KK)/256, 256, 0, stream>>>(emb, eT);
    vq_argmin_fused <<<NBLK,        256, 0, stream>>>(z, emb, eT, e2, out, part);
    vq_finalize     <<<1,           256, 0, stream>>>(part, out);
}